// Round 5
// baseline (100.797 us; speedup 1.0000x reference)
//
#include <hip/hip_runtime.h>

#define H        400
#define W_CROP   400
#define PSF_W    121
#define MARGIN   44
#define IM       488
#define NZ       64
#define N_EMIT   2048
#define PSF_AREA (PSF_W * PSF_W)     /* 14641 */
#define SIGMA2   100.0f              /* SIGMA_READ^2 */
#define TILE     16
#define TB       25                  /* tiles per side: 400/16 */
#define NTILES   (TB * TB)           /* 625 */
#define CAP      640                 /* max emitters per tile bin */
#define SPLIT    16                  /* chunks per tile */
#define MAXCHUNK (CAP / SPLIT)       /* 40 */
#define NPIX     (H * W_CROP)        /* 160000 */
#define WIN      9                   /* max tiles per dim an emitter touches */
#define PADW     152                 /* padded slice width (cols -16..135) */
#define PADA     (PADW * PADW)       /* 23104 elems per padded slice */

static __device__ __forceinline__ unsigned enc_ord(float f) {
    unsigned u = __float_as_uint(f);
    return (u & 0x80000000u) ? ~u : (u | 0x80000000u);
}
static __device__ __forceinline__ float dec_ord(unsigned u) {
    return __uint_as_float((u & 0x80000000u) ? (u & 0x7fffffffu) : ~u);
}

/* 64 blocks x 1024 thr: per-z PSF sums + build zero-padded PSF bank
   + zero out/counts + init minmax */
__global__ __launch_bounds__(1024) void init_zsum_kernel(
        const float* __restrict__ psf_bank, float* __restrict__ zmeta,
        int* __restrict__ counts, unsigned* __restrict__ minmax,
        float* __restrict__ out, float* __restrict__ pad)
{
    __shared__ float red[16][4];
    const int zi = blockIdx.x;
    const int gtid = zi * 1024 + threadIdx.x;

    for (int i = gtid; i < NPIX; i += 64 * 1024) out[i] = 0.0f;
    if (gtid < NTILES) counts[gtid] = 0;
    if (gtid == 0) { minmax[0] = 0xFFFFFFFFu; minmax[1] = 0u; }

    const float* __restrict__ src = psf_bank + (size_t)zi * PSF_AREA;
    float* __restrict__ dst = pad + (size_t)zi * PADA;

    /* padded copy: rows/cols -16..135 -> index 0..151 */
    for (int i = threadIdx.x; i < PADA; i += 1024) {
        const int r = i / PADW - 16;
        const int c = i - (i / PADW) * PADW - 16;
        const bool in = ((unsigned)r < (unsigned)PSF_W) && ((unsigned)c < (unsigned)PSF_W);
        dst[i] = in ? src[r * PSF_W + c] : 0.0f;
    }

    /* sums over original slice */
    float S = 0.f, R = 0.f, C = 0.f, K = 0.f;
    for (int i = threadIdx.x; i < PSF_AREA; i += 1024) {
        const float v = src[i];
        const int r = i / PSF_W;
        const int c = i - r * PSF_W;
        S += v;
        if (r == PSF_W - 1) R += v;
        if (c == PSF_W - 1) C += v;
        if (r == PSF_W - 1 && c == PSF_W - 1) K += v;
    }
    #pragma unroll
    for (int off = 32; off > 0; off >>= 1) {
        S += __shfl_down(S, off, 64);
        R += __shfl_down(R, off, 64);
        C += __shfl_down(C, off, 64);
        K += __shfl_down(K, off, 64);
    }
    const int wave = threadIdx.x >> 6, lane = threadIdx.x & 63;
    if (lane == 0) { red[wave][0] = S; red[wave][1] = R; red[wave][2] = C; red[wave][3] = K; }
    __syncthreads();
    if (threadIdx.x == 0) {
        float4 o = make_float4(0.f, 0.f, 0.f, 0.f);
        #pragma unroll
        for (int wv = 0; wv < 16; ++wv) {
            o.x += red[wv][0]; o.y += red[wv][1]; o.z += red[wv][2]; o.w += red[wv][3];
        }
        *(float4*)(zmeta + 4 * zi) = o;
    }
}

/* one thread per (emitter, window-slot); w==0 thread also writes emitter meta.
   grid = 2048*81/256 = 648 blocks exactly. */
__global__ __launch_bounds__(256) void emeta_bin_kernel(
        const float* __restrict__ xyz, const float* __restrict__ nph_arr,
        const float* __restrict__ zmeta, float* __restrict__ emeta,
        int* __restrict__ counts, unsigned short* __restrict__ bins)
{
    const int gid = blockIdx.x * 256 + threadIdx.x;
    const int e = gid / (WIN * WIN);
    const int w = gid - e * (WIN * WIN);

    const float x = xyz[3 * e + 0];
    const float y = xyz[3 * e + 1];
    const float lx = (x * 100.0f) / 11.0f;
    const float ly = (y * 100.0f) / 11.0f;
    const float r0f = (ly + 244.0f) - 60.5f;
    const float c0f = (lx + 244.0f) - 60.5f;
    const int   r0 = (int)floorf(r0f);
    const int   c0 = (int)floorf(c0f);

    const int trlo = max(0, (r0 - MARGIN) >> 4);
    const int trhi = min(TB - 1, (r0 + 76) >> 4);
    const int tclo = max(0, (c0 - MARGIN) >> 4);
    const int tchi = min(TB - 1, (c0 + 76) >> 4);

    const int tr = trlo + w / WIN;
    const int tc = tclo + (w - (w / WIN) * WIN);
    if (tr <= trhi && tc <= tchi) {
        const int t = tr * TB + tc;
        const int idx = atomicAdd(&counts[t], 1);
        if (idx < CAP) bins[(size_t)t * CAP + idx] = (unsigned short)e;
    }

    if (w == 0) {
        const float z = xyz[3 * e + 2];
        const float nph = nph_arr[e];
        int zi = (int)rintf((z + 2.0f) / 4.0f * 63.0f);
        zi = min(max(zi, 0), NZ - 1);
        const float rs = r0f - floorf(r0f);
        const float cs = c0f - floorf(c0f);
        const float4 zm = *(const float4*)(zmeta + 4 * zi);
        const float ssum = zm.x - rs * zm.y - cs * zm.z + rs * cs * zm.w;
        const float scale = nph / ssum;
        float4 m0, m1;
        m0.x = scale * (1.0f - rs) * (1.0f - cs);   /* w00 */
        m0.y = scale * (1.0f - rs) * cs;            /* w01 */
        m0.z = scale * rs * (1.0f - cs);            /* w10 */
        m0.w = scale * rs * cs;                     /* w11 */
        /* byte offset such that tcb + off = &pad[zi][pr0-1+16][pc+16] */
        const int off_elem = zi * PADA + (15 - r0) * PADW + (16 - c0);
        m1.x = __int_as_float(off_elem * 4);
        m1.y = 0.f; m1.z = 0.f; m1.w = 0.f;
        *(float4*)(emeta + 8 * e)     = m0;
        *(float4*)(emeta + 8 * e + 4) = m1;
    }
}

/* grid = NTILES*SPLIT single-wave blocks; thread = (col, 4-row strip).
   Padded PSF: no clamps/masks. Left column via DPP shfl_up, edge lanes reload. */
__global__ __launch_bounds__(64) void gather_kernel(
        const float* __restrict__ pad, const float* __restrict__ emeta,
        const int* __restrict__ counts, const unsigned short* __restrict__ bins,
        float* __restrict__ out)
{
    __shared__ float4 smeta[2 * MAXCHUNK];

    const int tile  = blockIdx.x >> 4;            /* SPLIT = 16 */
    const int chunk = blockIdx.x & (SPLIT - 1);
    const int tr = tile / TB, tc = tile - tr * TB;
    const int px = threadIdx.x & 15;              /* col within tile */
    const int wy = threadIdx.x >> 4;              /* 0..3: 4-row strip */
    const int orow0 = tr * TILE + wy * 4;
    const int ocol  = tc * TILE + px;
    const int crow0 = orow0 + MARGIN;
    const int ccol  = ocol + MARGIN;
    const int tcb   = (crow0 * PADW + ccol) * 4;  /* thread-constant byte offset */
    const char* __restrict__ pbase = (const char*)pad;

    const int n = min(counts[tile], CAP);
    const int nmine = (chunk < n) ? ((n - chunk + SPLIT - 1) / SPLIT) : 0;
    const unsigned short* __restrict__ bin = bins + (size_t)tile * CAP;

    for (int j = threadIdx.x; j < nmine * 8; j += 64) {
        const int jj = j >> 3, ww = j & 7;
        const int e = (int)bin[chunk + jj * SPLIT];
        ((float*)smeta)[jj * 8 + ww] = emeta[8 * e + ww];
    }
    __syncthreads();

    float acc0[4] = {0.f, 0.f, 0.f, 0.f};
    float acc1[4] = {0.f, 0.f, 0.f, 0.f};

    auto body = [&](int j, float* acc) {
        const float4 w = smeta[2 * j];
        const int off = __float_as_int(smeta[2 * j + 1].x);
        const char* __restrict__ p = pbase + (tcb + off);
        float a[5], b[5];
        #pragma unroll
        for (int i = 0; i < 5; ++i) a[i] = *(const float*)(p + i * (PADW * 4));
        #pragma unroll
        for (int i = 0; i < 5; ++i) b[i] = __shfl_up(a[i], 1, 16);
        if (px == 0) {
            #pragma unroll
            for (int i = 0; i < 5; ++i) b[i] = *(const float*)(p - 4 + i * (PADW * 4));
        }
        #pragma unroll
        for (int k = 0; k < 4; ++k) {
            float v = w.x * a[k + 1];            /* w00 * psf[pr  ][pc  ] */
            v = fmaf(w.y, b[k + 1], v);          /* w01 * psf[pr  ][pc-1] */
            v = fmaf(w.z, a[k],     v);          /* w10 * psf[pr-1][pc  ] */
            v = fmaf(w.w, b[k],     v);          /* w11 * psf[pr-1][pc-1] */
            acc[k] += v;
        }
    };

    int j = 0;
    for (; j + 2 <= nmine; j += 2) { body(j, acc0); body(j + 1, acc1); }
    for (; j < nmine; ++j) body(j, acc0);

    #pragma unroll
    for (int k = 0; k < 4; ++k) {
        const float acc = acc0[k] + acc1[k];
        if (acc != 0.f) atomicAdd(&out[(orow0 + k) * W_CROP + ocol], acc);
    }
}

/* float4: read accumulated image, apply noise, write back, reduce min/max */
__global__ __launch_bounds__(256) void noise_minmax_kernel(
        float* __restrict__ out, const float* __restrict__ noise,
        unsigned* __restrict__ minmax)
{
    const int i = blockIdx.x * 256 + threadIdx.x;
    float vmin = 1e30f, vmax = -1e30f;
    if (i < NPIX / 4) {
        float4 im = ((float4*)out)[i];
        const float4 nz = ((const float4*)noise)[i];
        im.x += sqrtf(fmaxf(im.x, 0.f) + SIGMA2) * nz.x;
        im.y += sqrtf(fmaxf(im.y, 0.f) + SIGMA2) * nz.y;
        im.z += sqrtf(fmaxf(im.z, 0.f) + SIGMA2) * nz.z;
        im.w += sqrtf(fmaxf(im.w, 0.f) + SIGMA2) * nz.w;
        ((float4*)out)[i] = im;
        vmin = fminf(fminf(im.x, im.y), fminf(im.z, im.w));
        vmax = fmaxf(fmaxf(im.x, im.y), fmaxf(im.z, im.w));
    }
    #pragma unroll
    for (int off = 32; off > 0; off >>= 1) {
        vmin = fminf(vmin, __shfl_down(vmin, off, 64));
        vmax = fmaxf(vmax, __shfl_down(vmax, off, 64));
    }
    if ((threadIdx.x & 63) == 0) {
        atomicMin(&minmax[0], enc_ord(vmin));
        atomicMax(&minmax[1], enc_ord(vmax));
    }
}

__global__ __launch_bounds__(256) void finalize_kernel(float* __restrict__ out,
                                                       const unsigned* __restrict__ minmax)
{
    const int i = blockIdx.x * 256 + threadIdx.x;
    if (i >= NPIX / 4) return;
    const float mn = dec_ord(minmax[0]);
    const float inv = 1.0f / (dec_ord(minmax[1]) - mn);
    float4 v = ((float4*)out)[i];
    v.x = (v.x - mn) * inv;
    v.y = (v.y - mn) * inv;
    v.z = (v.z - mn) * inv;
    v.w = (v.w - mn) * inv;
    ((float4*)out)[i] = v;
}

extern "C" void kernel_launch(void* const* d_in, const int* in_sizes, int n_in,
                              void* d_out, int out_size, void* d_ws, size_t ws_size,
                              hipStream_t stream) {
    const float* xyz      = (const float*)d_in[0];  /* (1,2048,3) */
    const float* nph      = (const float*)d_in[1];  /* (1,2048)   */
    /* d_in[2] = xy_center, unused by reference */
    const float* psf_bank = (const float*)d_in[3];  /* (64,121,121) */
    const float* noise    = (const float*)d_in[4];  /* (400,400) */
    float* out = (float*)d_out;

    /* ws layout (bytes):
       zmeta : 0       .. 1024        (64 * float4)
       emeta : 1024    .. 66560       (2048 * 8 floats)
       counts: 66560   .. 69120       (625 ints, padded)
       bins  : 69120   .. 869120      (625 * 640 * u16)
       minmax: 869120  .. 869128
       pad   : 870400  .. 6785024     (64 * 152 * 152 f32)          */
    char* ws = (char*)d_ws;
    float*          zmeta  = (float*)(ws + 0);
    float*          emeta  = (float*)(ws + 1024);
    int*            counts = (int*)(ws + 66560);
    unsigned short* bins   = (unsigned short*)(ws + 69120);
    unsigned*       minmax = (unsigned*)(ws + 869120);
    float*          pad    = (float*)(ws + 870400);

    init_zsum_kernel<<<NZ, 1024, 0, stream>>>(psf_bank, zmeta, counts, minmax, out, pad);
    emeta_bin_kernel<<<(N_EMIT * WIN * WIN) / 256, 256, 0, stream>>>(xyz, nph, zmeta, emeta, counts, bins);
    gather_kernel<<<NTILES * SPLIT, 64, 0, stream>>>(pad, emeta, counts, bins, out);
    noise_minmax_kernel<<<(NPIX / 4 + 255) / 256, 256, 0, stream>>>(out, noise, minmax);
    finalize_kernel<<<(NPIX / 4 + 255) / 256, 256, 0, stream>>>(out, minmax);
}

// Round 6
// 81.608 us; speedup vs baseline: 1.2351x; 1.2351x over previous
//
#include <hip/hip_runtime.h>

#define H        400
#define W_CROP   400
#define PSF_W    121
#define MARGIN   44
#define IM       488
#define NZ       64
#define N_EMIT   2048
#define PSF_AREA (PSF_W * PSF_W)     /* 14641 */
#define SIGMA2   100.0f              /* SIGMA_READ^2 */
#define TILE     16
#define TB       25                  /* tiles per side: 400/16 */
#define NTILES   (TB * TB)           /* 625 */
#define NPIX     (H * W_CROP)        /* 160000 */
#define WIN      9                   /* max tiles per dim an emitter touches */
#define PADW     152                 /* padded slice width (cols -16..135) */
#define PADA     (PADW * PADW)       /* 23104 elems per padded slice */
#define CHUNKS   4                   /* z-chunks per tile (zi>>4) */
#define CAPC     224                 /* max emitters per (tile, z-chunk) */

static __device__ __forceinline__ unsigned enc_ord(float f) {
    unsigned u = __float_as_uint(f);
    return (u & 0x80000000u) ? ~u : (u | 0x80000000u);
}
static __device__ __forceinline__ float dec_ord(unsigned u) {
    return __uint_as_float((u & 0x80000000u) ? (u & 0x7fffffffu) : ~u);
}

/* tiny init: zero counts (2500), zmeta (256 f), minmax */
__global__ __launch_bounds__(256) void zero_kernel(int* __restrict__ counts,
                                                   float* __restrict__ zmeta,
                                                   unsigned* __restrict__ minmax) {
    const int i = blockIdx.x * 256 + threadIdx.x;
    if (i < NTILES * CHUNKS) counts[i] = 0;
    if (i < NZ * 4) zmeta[i] = 0.0f;
    if (i == 0) { minmax[0] = 0xFFFFFFFFu; minmax[1] = 0u; }
}

/* 512 blocks: (z, part 0..7). Build padded slice part + partial sums -> atomicAdd zmeta. */
__global__ __launch_bounds__(256) void pad_zsum_kernel(
        const float* __restrict__ psf_bank, float* __restrict__ zmeta,
        float* __restrict__ pad)
{
    __shared__ float red[4][4];
    const int zi = blockIdx.x >> 3;
    const int part = blockIdx.x & 7;

    const float* __restrict__ src = psf_bank + (size_t)zi * PSF_AREA;
    float* __restrict__ dst = pad + (size_t)zi * PADA;

    /* padded copy: this part covers padded indices [part*2888, +2888) (2888 = 19*152) */
    const int plo = part * 2888;
    const int phi = min(plo + 2888, PADA);
    for (int i = plo + (int)threadIdx.x; i < phi; i += 256) {
        const int r = i / PADW - 16;
        const int c = i - (i / PADW) * PADW - 16;
        const bool in = ((unsigned)r < (unsigned)PSF_W) && ((unsigned)c < (unsigned)PSF_W);
        dst[i] = in ? src[r * PSF_W + c] : 0.0f;
    }

    /* partial sums over original slice: [part*1831, +1831) */
    const int slo = part * 1831;
    const int shi = min(slo + 1831, PSF_AREA);
    float S = 0.f, R = 0.f, C = 0.f, K = 0.f;
    for (int i = slo + (int)threadIdx.x; i < shi; i += 256) {
        const float v = src[i];
        const int r = i / PSF_W;
        const int c = i - r * PSF_W;
        S += v;
        if (r == PSF_W - 1) R += v;
        if (c == PSF_W - 1) C += v;
        if (r == PSF_W - 1 && c == PSF_W - 1) K += v;
    }
    #pragma unroll
    for (int off = 32; off > 0; off >>= 1) {
        S += __shfl_down(S, off, 64);
        R += __shfl_down(R, off, 64);
        C += __shfl_down(C, off, 64);
        K += __shfl_down(K, off, 64);
    }
    const int wave = threadIdx.x >> 6, lane = threadIdx.x & 63;
    if (lane == 0) { red[wave][0] = S; red[wave][1] = R; red[wave][2] = C; red[wave][3] = K; }
    __syncthreads();
    if (threadIdx.x < 4) {
        const float v = red[0][threadIdx.x] + red[1][threadIdx.x] +
                        red[2][threadIdx.x] + red[3][threadIdx.x];
        atomicAdd(&zmeta[4 * zi + threadIdx.x], v);
    }
}

/* one thread per (emitter, window-slot); w==0 thread also writes emitter meta. */
__global__ __launch_bounds__(256) void emeta_bin_kernel(
        const float* __restrict__ xyz, const float* __restrict__ nph_arr,
        const float* __restrict__ zmeta, float* __restrict__ emeta,
        int* __restrict__ counts, unsigned short* __restrict__ bins)
{
    const int gid = blockIdx.x * 256 + threadIdx.x;
    const int e = gid / (WIN * WIN);
    const int w = gid - e * (WIN * WIN);

    const float x = xyz[3 * e + 0];
    const float y = xyz[3 * e + 1];
    const float z = xyz[3 * e + 2];
    const float lx = (x * 100.0f) / 11.0f;
    const float ly = (y * 100.0f) / 11.0f;
    const float r0f = (ly + 244.0f) - 60.5f;
    const float c0f = (lx + 244.0f) - 60.5f;
    const int   r0 = (int)floorf(r0f);
    const int   c0 = (int)floorf(c0f);

    int zi = (int)rintf((z + 2.0f) / 4.0f * 63.0f);
    zi = min(max(zi, 0), NZ - 1);
    const int zc = zi >> 4;                      /* z-chunk 0..3 */

    const int trlo = max(0, (r0 - MARGIN) >> 4);
    const int trhi = min(TB - 1, (r0 + 76) >> 4);
    const int tclo = max(0, (c0 - MARGIN) >> 4);
    const int tchi = min(TB - 1, (c0 + 76) >> 4);

    const int tr = trlo + w / WIN;
    const int tc = tclo + (w - (w / WIN) * WIN);
    if (tr <= trhi && tc <= tchi) {
        const int t = (tr * TB + tc) * CHUNKS + zc;
        const int idx = atomicAdd(&counts[t], 1);
        if (idx < CAPC) bins[(size_t)t * CAPC + idx] = (unsigned short)e;
    }

    if (w == 0) {
        const float nph = nph_arr[e];
        const float rs = r0f - floorf(r0f);
        const float cs = c0f - floorf(c0f);
        const float4 zm = *(const float4*)(zmeta + 4 * zi);
        const float ssum = zm.x - rs * zm.y - cs * zm.z + rs * cs * zm.w;
        const float scale = nph / ssum;
        float4 m0, m1;
        m0.x = scale * (1.0f - rs) * (1.0f - cs);   /* w00 */
        m0.y = scale * (1.0f - rs) * cs;            /* w01 */
        m0.z = scale * rs * (1.0f - cs);            /* w10 */
        m0.w = scale * rs * cs;                     /* w11 */
        /* byte offset: tcb + off = &pad[zi][(crow0-r0)-1+16][(ccol-c0)+16] */
        const int off_elem = zi * PADA + (15 - r0) * PADW + (16 - c0);
        m1.x = __int_as_float(off_elem * 4);
        m1.y = 0.f; m1.z = 0.f; m1.w = 0.f;
        *(float4*)(emeta + 8 * e)     = m0;
        *(float4*)(emeta + 8 * e + 4) = m1;
    }
}

/* grid = NTILES*CHUNKS blocks x 256 thr. Block = (tile, z-chunk); its 4 waves
   interleave the chunk's emitter list stride-4 (same 16 z-slices -> L1/L2 reuse).
   Per lane: 4-row strip of one column. Padded PSF: no clamps. Left col via DPP.
   Block partial -> LDS reduce -> partial image (no global atomics). */
__global__ __launch_bounds__(256) void gather_kernel(
        const float* __restrict__ pad, const float* __restrict__ emeta,
        const int* __restrict__ counts, const unsigned short* __restrict__ bins,
        float* __restrict__ parts)
{
    __shared__ float4 smeta[2 * CAPC];           /* 7 KB */
    __shared__ float  tilepart[4][256];          /* 4 KB */

    const int tile = blockIdx.x >> 2;
    const int zc   = blockIdx.x & 3;
    const int tr = tile / TB, tc = tile - tr * TB;
    const int w    = threadIdx.x >> 6;
    const int lane = threadIdx.x & 63;
    const int px = lane & 15;                    /* col within tile */
    const int wy = lane >> 4;                    /* 0..3: 4-row strip */
    const int orow0 = tr * TILE + wy * 4;
    const int ocol  = tc * TILE + px;
    const int tcb   = ((orow0 + MARGIN) * PADW + (ocol + MARGIN)) * 4;
    const char* __restrict__ pbase = (const char*)pad;

    const int bidx = tile * CHUNKS + zc;
    const int n = min(counts[bidx], CAPC);
    const unsigned short* __restrict__ bin = bins + (size_t)bidx * CAPC;

    for (int i = threadIdx.x; i < n * 8; i += 256) {
        const int jj = i >> 3, ww = i & 7;
        const int e = (int)bin[jj];
        ((float*)smeta)[jj * 8 + ww] = emeta[8 * e + ww];
    }
    __syncthreads();

    float acc0[4] = {0.f, 0.f, 0.f, 0.f};
    float acc1[4] = {0.f, 0.f, 0.f, 0.f};

    auto body = [&](int j, float* acc) {
        const float4 wt = smeta[2 * j];
        const int off = __float_as_int(smeta[2 * j + 1].x);
        const char* __restrict__ p = pbase + (tcb + off);
        float a[5], b[5];
        #pragma unroll
        for (int i = 0; i < 5; ++i) a[i] = *(const float*)(p + i * (PADW * 4));
        #pragma unroll
        for (int i = 0; i < 5; ++i) b[i] = __shfl_up(a[i], 1, 16);
        if (px == 0) {
            #pragma unroll
            for (int i = 0; i < 5; ++i) b[i] = *(const float*)(p - 4 + i * (PADW * 4));
        }
        #pragma unroll
        for (int k = 0; k < 4; ++k) {
            float v = wt.x * a[k + 1];           /* w00 * psf[pr  ][pc  ] */
            v = fmaf(wt.y, b[k + 1], v);         /* w01 * psf[pr  ][pc-1] */
            v = fmaf(wt.z, a[k],     v);         /* w10 * psf[pr-1][pc  ] */
            v = fmaf(wt.w, b[k],     v);         /* w11 * psf[pr-1][pc-1] */
            acc[k] += v;
        }
    };

    int j = w;
    for (; j + 4 < n; j += 8) { body(j, acc0); body(j + 4, acc1); }
    if (j < n) body(j, acc0);

    #pragma unroll
    for (int k = 0; k < 4; ++k)
        tilepart[w][(wy * 4 + k) * 16 + px] = acc0[k] + acc1[k];
    __syncthreads();

    /* fixed-order reduce of the 4 waves, write partial image zc */
    const int row = threadIdx.x >> 4, col = threadIdx.x & 15;
    const float s = ((tilepart[0][threadIdx.x] + tilepart[1][threadIdx.x]) +
                     (tilepart[2][threadIdx.x] + tilepart[3][threadIdx.x]));
    parts[(size_t)zc * NPIX + (tr * TILE + row) * W_CROP + (tc * TILE + col)] = s;
}

/* sum 4 partial images (fixed order), apply noise, write out, reduce min/max */
__global__ __launch_bounds__(256) void noise_minmax_kernel(
        const float* __restrict__ parts, const float* __restrict__ noise,
        float* __restrict__ out, unsigned* __restrict__ minmax)
{
    const int i = blockIdx.x * 256 + threadIdx.x;
    float vmin = 1e30f, vmax = -1e30f;
    if (i < NPIX / 4) {
        const float4 p0 = ((const float4*)parts)[i];
        const float4 p1 = ((const float4*)(parts + NPIX))[i];
        const float4 p2 = ((const float4*)(parts + 2 * NPIX))[i];
        const float4 p3 = ((const float4*)(parts + 3 * NPIX))[i];
        float4 im;
        im.x = (p0.x + p1.x) + (p2.x + p3.x);
        im.y = (p0.y + p1.y) + (p2.y + p3.y);
        im.z = (p0.z + p1.z) + (p2.z + p3.z);
        im.w = (p0.w + p1.w) + (p2.w + p3.w);
        const float4 nz = ((const float4*)noise)[i];
        im.x += sqrtf(fmaxf(im.x, 0.f) + SIGMA2) * nz.x;
        im.y += sqrtf(fmaxf(im.y, 0.f) + SIGMA2) * nz.y;
        im.z += sqrtf(fmaxf(im.z, 0.f) + SIGMA2) * nz.z;
        im.w += sqrtf(fmaxf(im.w, 0.f) + SIGMA2) * nz.w;
        ((float4*)out)[i] = im;
        vmin = fminf(fminf(im.x, im.y), fminf(im.z, im.w));
        vmax = fmaxf(fmaxf(im.x, im.y), fmaxf(im.z, im.w));
    }
    #pragma unroll
    for (int off = 32; off > 0; off >>= 1) {
        vmin = fminf(vmin, __shfl_down(vmin, off, 64));
        vmax = fmaxf(vmax, __shfl_down(vmax, off, 64));
    }
    if ((threadIdx.x & 63) == 0) {
        atomicMin(&minmax[0], enc_ord(vmin));
        atomicMax(&minmax[1], enc_ord(vmax));
    }
}

__global__ __launch_bounds__(256) void finalize_kernel(float* __restrict__ out,
                                                       const unsigned* __restrict__ minmax)
{
    const int i = blockIdx.x * 256 + threadIdx.x;
    if (i >= NPIX / 4) return;
    const float mn = dec_ord(minmax[0]);
    const float inv = 1.0f / (dec_ord(minmax[1]) - mn);
    float4 v = ((float4*)out)[i];
    v.x = (v.x - mn) * inv;
    v.y = (v.y - mn) * inv;
    v.z = (v.z - mn) * inv;
    v.w = (v.w - mn) * inv;
    ((float4*)out)[i] = v;
}

extern "C" void kernel_launch(void* const* d_in, const int* in_sizes, int n_in,
                              void* d_out, int out_size, void* d_ws, size_t ws_size,
                              hipStream_t stream) {
    const float* xyz      = (const float*)d_in[0];  /* (1,2048,3) */
    const float* nph      = (const float*)d_in[1];  /* (1,2048)   */
    /* d_in[2] = xy_center, unused by reference */
    const float* psf_bank = (const float*)d_in[3];  /* (64,121,121) */
    const float* noise    = (const float*)d_in[4];  /* (400,400) */
    float* out = (float*)d_out;

    /* ws layout (bytes):
       zmeta : 0        .. 1024       (64 * float4)
       emeta : 1024     .. 66560      (2048 * 8 floats)
       counts: 66560    .. 76560      (2500 ints)
       minmax: 76560    .. 76568
       pad   : 76800    .. 5991424    (64 * 152 * 152 f32)
       bins  : 5991424  .. 7111424    (625*4*224 u16)
       parts : 7111424  .. 9671424    (4 * 400*400 f32)            */
    char* ws = (char*)d_ws;
    float*          zmeta  = (float*)(ws + 0);
    float*          emeta  = (float*)(ws + 1024);
    int*            counts = (int*)(ws + 66560);
    unsigned*       minmax = (unsigned*)(ws + 76560);
    float*          pad    = (float*)(ws + 76800);
    unsigned short* bins   = (unsigned short*)(ws + 5991424);
    float*          parts  = (float*)(ws + 7111424);

    zero_kernel<<<10, 256, 0, stream>>>(counts, zmeta, minmax);
    pad_zsum_kernel<<<NZ * 8, 256, 0, stream>>>(psf_bank, zmeta, pad);
    emeta_bin_kernel<<<(N_EMIT * WIN * WIN) / 256, 256, 0, stream>>>(xyz, nph, zmeta, emeta, counts, bins);
    gather_kernel<<<NTILES * CHUNKS, 256, 0, stream>>>(pad, emeta, counts, bins, parts);
    noise_minmax_kernel<<<(NPIX / 4 + 255) / 256, 256, 0, stream>>>(parts, noise, out, minmax);
    finalize_kernel<<<(NPIX / 4 + 255) / 256, 256, 0, stream>>>(out, minmax);
}

// Round 7
// 78.063 us; speedup vs baseline: 1.2912x; 1.0454x over previous
//
#include <hip/hip_runtime.h>

#define H        400
#define W_CROP   400
#define PSF_W    121
#define MARGIN   44
#define IM       488
#define NZ       64
#define N_EMIT   2048
#define PSF_AREA (PSF_W * PSF_W)     /* 14641 */
#define SIGMA2   100.0f              /* SIGMA_READ^2 */
#define TILE     16
#define TB       25                  /* tiles per side: 400/16 */
#define NTILES   (TB * TB)           /* 625 */
#define NPIX     (H * W_CROP)        /* 160000 */
#define WIN      9                   /* max tiles per dim an emitter touches */
#define PADW     152                 /* padded slice width (rows/cols -16..135) */
#define PADA     (PADW * PADW)       /* 23104 elems per padded slice */
#define CHUNKS   4                   /* z-chunks per tile (zi>>4) */
#define CAPC     224                 /* max emitters per (tile, z-chunk) */

static __device__ __forceinline__ unsigned enc_ord(float f) {
    unsigned u = __float_as_uint(f);
    return (u & 0x80000000u) ? ~u : (u | 0x80000000u);
}
static __device__ __forceinline__ float dec_ord(unsigned u) {
    return __uint_as_float((u & 0x80000000u) ? (u & 0x7fffffffu) : ~u);
}

/* 512 blocks: (z, part 0..7). Build padded-slice part + per-part sums -> zpart.
   Also zeroes counts and inits minmax (blocks 0..9). No atomics. */
__global__ __launch_bounds__(256) void pad_zsum_kernel(
        const float* __restrict__ psf_bank, float* __restrict__ zpart,
        float* __restrict__ pad, int* __restrict__ counts,
        unsigned* __restrict__ minmax)
{
    __shared__ float red[4][4];
    const int zi   = blockIdx.x >> 3;
    const int part = blockIdx.x & 7;
    const int gid  = blockIdx.x * 256 + threadIdx.x;

    if (gid < NTILES * CHUNKS) counts[gid] = 0;
    if (gid == 0) { minmax[0] = 0xFFFFFFFFu; minmax[1] = 0u; }

    const float* __restrict__ src = psf_bank + (size_t)zi * PSF_AREA;
    float* __restrict__ dst = pad + (size_t)zi * PADA;

    /* padded copy: this part covers padded indices [part*2888, +2888) (2888 = 19*152) */
    const int plo = part * 2888;
    const int phi = min(plo + 2888, PADA);
    for (int i = plo + (int)threadIdx.x; i < phi; i += 256) {
        const int r = i / PADW - 16;
        const int c = i - (i / PADW) * PADW - 16;
        const bool in = ((unsigned)r < (unsigned)PSF_W) && ((unsigned)c < (unsigned)PSF_W);
        dst[i] = in ? src[r * PSF_W + c] : 0.0f;
    }

    /* partial sums over original slice: [part*1831, +1831) */
    const int slo = part * 1831;
    const int shi = min(slo + 1831, PSF_AREA);
    float S = 0.f, R = 0.f, C = 0.f, K = 0.f;
    for (int i = slo + (int)threadIdx.x; i < shi; i += 256) {
        const float v = src[i];
        const int r = i / PSF_W;
        const int c = i - r * PSF_W;
        S += v;
        if (r == PSF_W - 1) R += v;
        if (c == PSF_W - 1) C += v;
        if (r == PSF_W - 1 && c == PSF_W - 1) K += v;
    }
    #pragma unroll
    for (int off = 32; off > 0; off >>= 1) {
        S += __shfl_down(S, off, 64);
        R += __shfl_down(R, off, 64);
        C += __shfl_down(C, off, 64);
        K += __shfl_down(K, off, 64);
    }
    const int wave = threadIdx.x >> 6, lane = threadIdx.x & 63;
    if (lane == 0) { red[wave][0] = S; red[wave][1] = R; red[wave][2] = C; red[wave][3] = K; }
    __syncthreads();
    if (threadIdx.x == 0) {
        float4 o;
        o.x = (red[0][0] + red[1][0]) + (red[2][0] + red[3][0]);
        o.y = (red[0][1] + red[1][1]) + (red[2][1] + red[3][1]);
        o.z = (red[0][2] + red[1][2]) + (red[2][2] + red[3][2]);
        o.w = (red[0][3] + red[1][3]) + (red[2][3] + red[3][3]);
        *(float4*)(zpart + (size_t)(zi * 8 + part) * 4) = o;
    }
}

/* one thread per (emitter, window-slot); w==0 thread also writes emitter meta. */
__global__ __launch_bounds__(256) void emeta_bin_kernel(
        const float* __restrict__ xyz, const float* __restrict__ nph_arr,
        const float* __restrict__ zpart, float* __restrict__ emeta,
        int* __restrict__ counts, unsigned short* __restrict__ bins)
{
    const int gid = blockIdx.x * 256 + threadIdx.x;
    const int e = gid / (WIN * WIN);
    const int w = gid - e * (WIN * WIN);

    const float x = xyz[3 * e + 0];
    const float y = xyz[3 * e + 1];
    const float z = xyz[3 * e + 2];
    const float lx = (x * 100.0f) / 11.0f;
    const float ly = (y * 100.0f) / 11.0f;
    const float r0f = (ly + 244.0f) - 60.5f;
    const float c0f = (lx + 244.0f) - 60.5f;
    const int   r0 = (int)floorf(r0f);
    const int   c0 = (int)floorf(c0f);

    int zi = (int)rintf((z + 2.0f) / 4.0f * 63.0f);
    zi = min(max(zi, 0), NZ - 1);
    const int zc = zi >> 4;                      /* z-chunk 0..3 */

    const int trlo = max(0, (r0 - MARGIN) >> 4);
    const int trhi = min(TB - 1, (r0 + 76) >> 4);
    const int tclo = max(0, (c0 - MARGIN) >> 4);
    const int tchi = min(TB - 1, (c0 + 76) >> 4);

    const int tr = trlo + w / WIN;
    const int tc = tclo + (w - (w / WIN) * WIN);
    if (tr <= trhi && tc <= tchi) {
        const int t = (tr * TB + tc) * CHUNKS + zc;
        const int idx = atomicAdd(&counts[t], 1);
        if (idx < CAPC) bins[(size_t)t * CAPC + idx] = (unsigned short)e;
    }

    if (w == 0) {
        const float nph = nph_arr[e];
        const float rs = r0f - floorf(r0f);
        const float cs = c0f - floorf(c0f);
        /* sum the 8 per-part z-slice partials (fixed order, deterministic) */
        const float4* __restrict__ zp = (const float4*)zpart + zi * 8;
        float4 zm = make_float4(0.f, 0.f, 0.f, 0.f);
        #pragma unroll
        for (int q = 0; q < 8; ++q) {
            const float4 t = zp[q];
            zm.x += t.x; zm.y += t.y; zm.z += t.z; zm.w += t.w;
        }
        const float ssum = zm.x - rs * zm.y - cs * zm.z + rs * cs * zm.w;
        const float scale = nph / ssum;
        float4 m0, m1;
        m0.x = scale * (1.0f - rs) * (1.0f - cs);   /* w00 */
        m0.y = scale * (1.0f - rs) * cs;            /* w01 */
        m0.z = scale * rs * (1.0f - cs);            /* w10 */
        m0.w = scale * rs * cs;                     /* w11 */
        /* byte offset: tcb + off = &pad[zi][(crow-r0)-1+16][(ccol-c0)+16] */
        const int off_elem = zi * PADA + (15 - r0) * PADW + (16 - c0);
        m1.x = __int_as_float(off_elem * 4);
        m1.y = __int_as_float(r0);
        m1.z = __int_as_float(c0);
        m1.w = 0.f;
        *(float4*)(emeta + 8 * e)     = m0;
        *(float4*)(emeta + 8 * e + 4) = m1;
    }
}

/* grid = NTILES*CHUNKS blocks x 256 thr. Block = (tile, z-chunk); its 4 waves
   interleave the chunk's emitter list mod 4 (same 16 z-slices -> L2 reuse).
   Per lane: 4-row strip of one column. Padded PSF handles -1 taps; explicit
   mask crops to the 121x121 footprint (reference crops the shifted PSF).
   Block partial -> LDS reduce -> partial image zc (no global atomics). */
__global__ __launch_bounds__(256) void gather_kernel(
        const float* __restrict__ pad, const float* __restrict__ emeta,
        const int* __restrict__ counts, const unsigned short* __restrict__ bins,
        float* __restrict__ parts)
{
    __shared__ float4 smeta[2 * CAPC];           /* 7 KB */
    __shared__ float  tilepart[4][256];          /* 4 KB */

    const int tile = blockIdx.x >> 2;
    const int zc   = blockIdx.x & 3;
    const int tr = tile / TB, tc = tile - tr * TB;
    const int w    = threadIdx.x >> 6;
    const int lane = threadIdx.x & 63;
    const int px = lane & 15;                    /* col within tile */
    const int wy = lane >> 4;                    /* 0..3: 4-row strip */
    const int orow0 = tr * TILE + wy * 4;
    const int ocol  = tc * TILE + px;
    const int crow0 = orow0 + MARGIN;            /* canvas coords */
    const int ccol  = ocol + MARGIN;
    const int tcb   = (crow0 * PADW + ccol) * 4; /* thread-constant byte offset */
    const char* __restrict__ pbase = (const char*)pad;

    const int bidx = tile * CHUNKS + zc;
    const int n = min(counts[bidx], CAPC);
    const unsigned short* __restrict__ bin = bins + (size_t)bidx * CAPC;

    for (int i = threadIdx.x; i < n * 8; i += 256) {
        const int jj = i >> 3, ww = i & 7;
        const int e = (int)bin[jj];
        ((float*)smeta)[jj * 8 + ww] = emeta[8 * e + ww];
    }
    __syncthreads();

    float acc0[4] = {0.f, 0.f, 0.f, 0.f};
    float acc1[4] = {0.f, 0.f, 0.f, 0.f};

    auto body = [&](int j, float* acc) {
        const float4 wt = smeta[2 * j];
        const float4 mm = smeta[2 * j + 1];
        const int off = __float_as_int(mm.x);
        const int pr0 = crow0 - __float_as_int(mm.y);   /* row offset of strip pixel 0 */
        const int pc  = ccol  - __float_as_int(mm.z);
        const char* __restrict__ p = pbase + (tcb + off);
        float a[5], b[5];
        #pragma unroll
        for (int i = 0; i < 5; ++i) a[i] = *(const float*)(p + i * (PADW * 4));
        #pragma unroll
        for (int i = 0; i < 5; ++i) b[i] = __shfl_up(a[i], 1, 16);
        if (px == 0) {
            #pragma unroll
            for (int i = 0; i < 5; ++i) b[i] = *(const float*)(p - 4 + i * (PADW * 4));
        }
        const bool pcok = (unsigned)pc <= 120u;
        #pragma unroll
        for (int k = 0; k < 4; ++k) {
            float v = wt.x * a[k + 1];           /* w00 * psf[pr  ][pc  ] */
            v = fmaf(wt.y, b[k + 1], v);         /* w01 * psf[pr  ][pc-1] */
            v = fmaf(wt.z, a[k],     v);         /* w10 * psf[pr-1][pc  ] */
            v = fmaf(wt.w, b[k],     v);         /* w11 * psf[pr-1][pc-1] */
            /* crop to footprint: reference adds only rows/cols 0..120 */
            if (pcok & ((unsigned)(pr0 + k) <= 120u)) acc[k] += v;
        }
    };

    int j = w;
    for (; j + 4 < n; j += 8) { body(j, acc0); body(j + 4, acc1); }
    if (j < n) body(j, acc0);

    #pragma unroll
    for (int k = 0; k < 4; ++k)
        tilepart[w][(wy * 4 + k) * 16 + px] = acc0[k] + acc1[k];
    __syncthreads();

    /* fixed-order reduce of the 4 waves, write partial image zc */
    const int row = threadIdx.x >> 4, col = threadIdx.x & 15;
    const float s = ((tilepart[0][threadIdx.x] + tilepart[1][threadIdx.x]) +
                     (tilepart[2][threadIdx.x] + tilepart[3][threadIdx.x]));
    parts[(size_t)zc * NPIX + (tr * TILE + row) * W_CROP + (tc * TILE + col)] = s;
}

/* sum 4 partial images (fixed order), apply noise, write out, reduce min/max */
__global__ __launch_bounds__(256) void noise_minmax_kernel(
        const float* __restrict__ parts, const float* __restrict__ noise,
        float* __restrict__ out, unsigned* __restrict__ minmax)
{
    const int i = blockIdx.x * 256 + threadIdx.x;
    float vmin = 1e30f, vmax = -1e30f;
    if (i < NPIX / 4) {
        const float4 p0 = ((const float4*)parts)[i];
        const float4 p1 = ((const float4*)(parts + NPIX))[i];
        const float4 p2 = ((const float4*)(parts + 2 * NPIX))[i];
        const float4 p3 = ((const float4*)(parts + 3 * NPIX))[i];
        float4 im;
        im.x = (p0.x + p1.x) + (p2.x + p3.x);
        im.y = (p0.y + p1.y) + (p2.y + p3.y);
        im.z = (p0.z + p1.z) + (p2.z + p3.z);
        im.w = (p0.w + p1.w) + (p2.w + p3.w);
        const float4 nz = ((const float4*)noise)[i];
        im.x += sqrtf(fmaxf(im.x, 0.f) + SIGMA2) * nz.x;
        im.y += sqrtf(fmaxf(im.y, 0.f) + SIGMA2) * nz.y;
        im.z += sqrtf(fmaxf(im.z, 0.f) + SIGMA2) * nz.z;
        im.w += sqrtf(fmaxf(im.w, 0.f) + SIGMA2) * nz.w;
        ((float4*)out)[i] = im;
        vmin = fminf(fminf(im.x, im.y), fminf(im.z, im.w));
        vmax = fmaxf(fmaxf(im.x, im.y), fmaxf(im.z, im.w));
    }
    #pragma unroll
    for (int off = 32; off > 0; off >>= 1) {
        vmin = fminf(vmin, __shfl_down(vmin, off, 64));
        vmax = fmaxf(vmax, __shfl_down(vmax, off, 64));
    }
    if ((threadIdx.x & 63) == 0) {
        atomicMin(&minmax[0], enc_ord(vmin));
        atomicMax(&minmax[1], enc_ord(vmax));
    }
}

__global__ __launch_bounds__(256) void finalize_kernel(float* __restrict__ out,
                                                       const unsigned* __restrict__ minmax)
{
    const int i = blockIdx.x * 256 + threadIdx.x;
    if (i >= NPIX / 4) return;
    const float mn = dec_ord(minmax[0]);
    const float inv = 1.0f / (dec_ord(minmax[1]) - mn);
    float4 v = ((float4*)out)[i];
    v.x = (v.x - mn) * inv;
    v.y = (v.y - mn) * inv;
    v.z = (v.z - mn) * inv;
    v.w = (v.w - mn) * inv;
    ((float4*)out)[i] = v;
}

extern "C" void kernel_launch(void* const* d_in, const int* in_sizes, int n_in,
                              void* d_out, int out_size, void* d_ws, size_t ws_size,
                              hipStream_t stream) {
    const float* xyz      = (const float*)d_in[0];  /* (1,2048,3) */
    const float* nph      = (const float*)d_in[1];  /* (1,2048)   */
    /* d_in[2] = xy_center, unused by reference */
    const float* psf_bank = (const float*)d_in[3];  /* (64,121,121) */
    const float* noise    = (const float*)d_in[4];  /* (400,400) */
    float* out = (float*)d_out;

    /* ws layout (bytes):
       emeta : 0        .. 65536      (2048 * 8 floats)
       counts: 65536    .. 75536      (2500 ints)
       minmax: 75536    .. 75544
       zpart : 75776    .. 83968      (64 * 8 * float4)
       pad   : 84480    .. 5999104    (64 * 152 * 152 f32)
       bins  : 5999104  .. 7119104    (625*4*224 u16)
       parts : 7119104  .. 9679104    (4 * 400*400 f32)            */
    char* ws = (char*)d_ws;
    float*          emeta  = (float*)(ws + 0);
    int*            counts = (int*)(ws + 65536);
    unsigned*       minmax = (unsigned*)(ws + 75536);
    float*          zpart  = (float*)(ws + 75776);
    float*          pad    = (float*)(ws + 84480);
    unsigned short* bins   = (unsigned short*)(ws + 5999104);
    float*          parts  = (float*)(ws + 7119104);

    pad_zsum_kernel<<<NZ * 8, 256, 0, stream>>>(psf_bank, zpart, pad, counts, minmax);
    emeta_bin_kernel<<<(N_EMIT * WIN * WIN) / 256, 256, 0, stream>>>(xyz, nph, zpart, emeta, counts, bins);
    gather_kernel<<<NTILES * CHUNKS, 256, 0, stream>>>(pad, emeta, counts, bins, parts);
    noise_minmax_kernel<<<(NPIX / 4 + 255) / 256, 256, 0, stream>>>(parts, noise, out, minmax);
    finalize_kernel<<<(NPIX / 4 + 255) / 256, 256, 0, stream>>>(out, minmax);
}